// Round 2
// baseline (357.406 us; speedup 1.0000x reference)
//
#include <hip/hip_runtime.h>

#define NV 300000
#define KT 9
#define NF 64
#define NBLK ((NV + 63) / 64)   // 4688 blocks of 64 rows

typedef __attribute__((ext_vector_type(8))) short bf16x8;
typedef __attribute__((ext_vector_type(4))) float f32x4;
typedef __attribute__((ext_vector_type(4))) float f4;
typedef __attribute__((ext_vector_type(4))) unsigned short u16x4;

// round-to-nearest-even f32 -> bf16 bits
__device__ __forceinline__ unsigned short f2bf(float f) {
    union { float f; unsigned int u; } a; a.f = f;
    unsigned int u = a.u;
    return (unsigned short)((u + 0x7FFFu + ((u >> 16) & 1u)) >> 16);
}

// prep: blocks 0..17 transpose+cvt weights (w[k][f][o] -> wt[k][o][f] bf16),
//       blocks 18..  convert relu(lv) -> bf16
__global__ void prep_kernel(const float* __restrict__ lv,
                            const float* __restrict__ w1,
                            const float* __restrict__ w2,
                            unsigned short* __restrict__ xbf0,
                            unsigned short* __restrict__ wt1,
                            unsigned short* __restrict__ wt2) {
    int b = blockIdx.x;
    if (b < 18) {
        const float* w = (b < 9) ? w1 : w2;
        unsigned short* wt = (b < 9) ? wt1 : wt2;
        int k = (b < 9) ? b : b - 9;
        for (int e = threadIdx.x; e < NF * NF; e += 256) {
            int o = e >> 6, f = e & 63;
            wt[(k * NF + o) * NF + f] = f2bf(w[(k * NF + f) * NF + o]);
        }
    } else {
        const int n4 = NV * NF / 4;
        const int stride = (gridDim.x - 18) * 256;
        for (int i = (b - 18) * 256 + threadIdx.x; i < n4; i += stride) {
            f4 v = ((const f4*)lv)[i];
            u16x4 r;
            #pragma unroll
            for (int j = 0; j < 4; ++j) r[j] = f2bf(fmaxf(v[j], 0.f));
            ((u16x4*)xbf0)[i] = r;
        }
    }
}

// One lattice conv layer: out[n,o] = sum_k sum_f xin[nbr[n,k], f] * w[k][f][o] (+bias)
// LAYER==1: bfout = bf16(relu(conv + b))     (feeds next layer's gather)
// LAYER==2: fout  = conv + b + resid         (fp32 final output)
template<int LAYER>
__global__ __launch_bounds__(256)
void conv_kernel(const unsigned short* __restrict__ xin,  // bf16 bits [NV][64]
                 const int* __restrict__ nbr,             // [NV][9]
                 const unsigned short* __restrict__ wt,   // bf16 [9][64][64], o-major
                 const float* __restrict__ bias,          // [64]
                 const float* __restrict__ resid,         // [NV][64] (LAYER==2)
                 unsigned short* __restrict__ bfout,      // LAYER==1
                 float* __restrict__ fout)                // LAYER==2
{
    // gathered A tile, chunk-major: gA[buf][chunk(8)][row(64)][8 bf16]
    // row r of chunk c stored at slot (r ^ c)  -> conflict-free b128 reads
    __shared__ unsigned short gA[2][4096];   // 2 x 8 KiB
    __shared__ int nbs[576];                 // 64 rows x 9 taps

    const int tid  = threadIdx.x;
    const int lane = tid & 63;
    const int wv   = tid >> 6;               // wave 0..3 -> output cols wv*16..+15
    const int base = blockIdx.x * 64;

    // neighbor tile -> LDS
    for (int e = tid; e < 576; e += 256) {
        long ge = (long)base * 9 + e;
        nbs[e] = (ge < (long)NV * 9) ? nbr[ge] : 0;
    }

    // all 18 B fragments in registers: lane l, reg j holds w[k][kk*32+(l>>4)*8+j][wv*16+(l&15)]
    const int bcol = wv * 16 + (lane & 15);
    const int bk   = (lane >> 4) * 8;
    bf16x8 bw[KT][2];
    #pragma unroll
    for (int k = 0; k < KT; ++k) {
        #pragma unroll
        for (int kk = 0; kk < 2; ++kk)
            bw[k][kk] = *(const bf16x8*)&wt[(k * 64 + bcol) * 64 + kk * 32 + bk];
    }

    f32x4 acc[4];
    #pragma unroll
    for (int im = 0; im < 4; ++im) acc[im] = (f32x4){0.f, 0.f, 0.f, 0.f};

    __syncthreads();   // nbs ready

    // stage tap k's 64 gathered rows into gA[buf] via global_load_lds(16B):
    // wave wv covers chunks c = wv, wv+4; lane l fetches row (l ^ c), writes LDS linearly.
    auto stage = [&](int k, int buf) {
        #pragma unroll
        for (int h = 0; h < 2; ++h) {
            const int c = wv + h * 4;
            const int r = lane ^ c;
            const int nb = nbs[r * 9 + k];
            const unsigned short* src = xin + nb * 64 + c * 8;
            __builtin_amdgcn_global_load_lds(
                (const __attribute__((address_space(1))) unsigned int*)src,
                (__attribute__((address_space(3))) unsigned int*)&gA[buf][c * 512],
                16, 0, 0);
        }
    };

    stage(0, 0);
    asm volatile("s_waitcnt vmcnt(0)" ::: "memory");
    __syncthreads();

    #pragma unroll
    for (int k = 0; k < KT; ++k) {
        const int cur = k & 1;
        if (k < KT - 1) stage(k + 1, cur ^ 1);   // prefetch next tap
        #pragma unroll
        for (int im = 0; im < 4; ++im) {
            #pragma unroll
            for (int kk = 0; kk < 2; ++kk) {
                const int chunk = kk * 4 + (lane >> 4);
                const int row   = im * 16 + (lane & 15);
                bf16x8 a = *(const bf16x8*)&gA[cur][(chunk * 64 + (row ^ chunk)) * 8];
                acc[im] = __builtin_amdgcn_mfma_f32_16x16x32_bf16(a, bw[k][kk], acc[im], 0, 0, 0);
            }
        }
        asm volatile("s_waitcnt vmcnt(0)" ::: "memory");
        __syncthreads();
    }

    // epilogue: D lane layout col = lane&15, row = (lane>>4)*4 + j  (within 16x16 tile)
    const int ocol = wv * 16 + (lane & 15);
    const int orow = (lane >> 4) * 4;
    const float bv = bias[ocol];
    #pragma unroll
    for (int im = 0; im < 4; ++im) {
        #pragma unroll
        for (int j = 0; j < 4; ++j) {
            const int r = base + im * 16 + orow + j;
            if (r < NV) {
                float v = acc[im][j] + bv;
                if (LAYER == 1) {
                    bfout[r * 64 + ocol] = f2bf(fmaxf(v, 0.f));
                } else {
                    fout[r * 64 + ocol] = v + resid[r * 64 + ocol];
                }
            }
        }
    }
}

extern "C" void kernel_launch(void* const* d_in, const int* in_sizes, int n_in,
                              void* d_out, int out_size, void* d_ws, size_t ws_size,
                              hipStream_t stream) {
    const float* lv  = (const float*)d_in[0];
    const int*   nbr = (const int*)d_in[1];
    const float* w1  = (const float*)d_in[2];
    const float* b1  = (const float*)d_in[3];
    const float* w2  = (const float*)d_in[4];
    const float* b2  = (const float*)d_in[5];
    float* out = (float*)d_out;

    // workspace layout (needs ~73.4 MiB)
    char* ws = (char*)d_ws;
    unsigned short* xbf0 = (unsigned short*)ws;                // 38,400,000 B: bf16 relu(lv)
    unsigned short* xbf1 = (unsigned short*)(ws + 38400000);   // 38,400,000 B: bf16 relu(y1)
    unsigned short* wt1  = (unsigned short*)(ws + 76800000);   // 73,728 B
    unsigned short* wt2  = (unsigned short*)(ws + 76873728);   // 73,728 B

    prep_kernel<<<18 + 2048, 256, 0, stream>>>(lv, w1, w2, xbf0, wt1, wt2);
    conv_kernel<1><<<NBLK, 256, 0, stream>>>(xbf0, nbr, wt1, b1, nullptr, xbf1, nullptr);
    conv_kernel<2><<<NBLK, 256, 0, stream>>>(xbf1, nbr, wt2, b2, lv, nullptr, out);
}

// Round 4
// 325.808 us; speedup vs baseline: 1.0970x; 1.0970x over previous
//
#include <hip/hip_runtime.h>

#define NV 300000
#define KT 9
#define NF 64
#define NBLK ((NV + 63) / 64)   // 4688 blocks of 64 rows

typedef __attribute__((ext_vector_type(8))) short bf16x8;
typedef __attribute__((ext_vector_type(4))) float f32x4;
typedef __attribute__((ext_vector_type(4))) float f4;
typedef __attribute__((ext_vector_type(4))) unsigned short u16x4;

// round-to-nearest-even f32 -> bf16 bits
__device__ __forceinline__ unsigned short f2bf(float f) {
    union { float f; unsigned int u; } a; a.f = f;
    unsigned int u = a.u;
    return (unsigned short)((u + 0x7FFFu + ((u >> 16) & 1u)) >> 16);
}

// prep part 1: transpose+cvt weights (w[k][f][o] -> wt[k][o][f] bf16), 18 blocks
__global__ void prep_w_kernel(const float* __restrict__ w1,
                              const float* __restrict__ w2,
                              unsigned short* __restrict__ wt1,
                              unsigned short* __restrict__ wt2) {
    int b = blockIdx.x;
    const float* w = (b < 9) ? w1 : w2;
    unsigned short* wt = (b < 9) ? wt1 : wt2;
    int k = (b < 9) ? b : b - 9;
    for (int e = threadIdx.x; e < NF * NF; e += 256) {
        int o = e >> 6, f = e & 63;
        wt[(k * NF + o) * NF + f] = f2bf(w[(k * NF + f) * NF + o]);
    }
}

// prep part 2: relu(lv) -> bf16, one f4 per thread (exact grid)
__global__ void prep_x_kernel(const float* __restrict__ lv,
                              unsigned short* __restrict__ xbf0) {
    const int n4 = NV * NF / 4;   // 4,800,000
    int i = blockIdx.x * 256 + threadIdx.x;
    if (i < n4) {
        f4 v = ((const f4*)lv)[i];
        u16x4 r;
        #pragma unroll
        for (int j = 0; j < 4; ++j) r[j] = f2bf(fmaxf(v[j], 0.f));
        ((u16x4*)xbf0)[i] = r;
    }
}

// One lattice conv layer: out[n,o] = sum_k sum_f xin[nbr[n,k], f] * w[k][f][o] (+bias)
// LAYER==1: bfout = bf16(relu(conv + b))     (feeds next layer's gather)
// LAYER==2: fout  = conv + b + resid         (fp32 final output)
//
// Gather layout: per tap, row-major LDS tile [64 rows][64 bf16] with XOR col
// swizzle: LDS(r, c16) holds global 16B-chunk (c16 ^ (r&7)) of the gathered
// row. Staged via global_load_lds width=16: 8 consecutive lanes cover one
// row's 128B (source pre-swizzled) -> full line coalescing, LDS dest linear.
template<int LAYER>
__global__ __launch_bounds__(256, 4)
void conv_kernel(const unsigned short* __restrict__ xin,  // bf16 bits [NV][64]
                 const int* __restrict__ nbr,             // [NV][9]
                 const unsigned short* __restrict__ wt,   // bf16 [9][64][64], o-major
                 const float* __restrict__ bias,          // [64]
                 const float* __restrict__ resid,         // [NV][64] (LAYER==2)
                 unsigned short* __restrict__ bfout,      // LAYER==1
                 float* __restrict__ fout)                // LAYER==2
{
    __shared__ unsigned short gA[4][64][64];  // 4 rotating tap buffers, 8 KiB each
    __shared__ int nbs[576];                  // 64 rows x 9 taps

    const int tid  = threadIdx.x;
    const int lane = tid & 63;
    const int wv   = tid >> 6;               // wave 0..3 -> output cols wv*16..+15
    const int base = blockIdx.x * 64;

    // neighbor tile -> LDS
    for (int e = tid; e < 576; e += 256) {
        long ge = (long)base * 9 + e;
        nbs[e] = (ge < (long)NV * 9) ? nbr[ge] : 0;
    }

    // all 18 B fragments in registers: lane l, reg j holds w[k][kk*32+(l>>4)*8+j][wv*16+(l&15)]
    const int bcol = wv * 16 + (lane & 15);
    const int bk   = (lane >> 4) * 8;
    bf16x8 bw[KT][2];
    #pragma unroll
    for (int k = 0; k < KT; ++k) {
        #pragma unroll
        for (int kk = 0; kk < 2; ++kk)
            bw[k][kk] = *(const bf16x8*)&wt[(k * 64 + bcol) * 64 + kk * 32 + bk];
    }

    f32x4 acc[4];
    #pragma unroll
    for (int im = 0; im < 4; ++im) acc[im] = (f32x4){0.f, 0.f, 0.f, 0.f};

    __syncthreads();   // nbs ready

    // stage tap k: wave wv instruction h covers rows (wv+h*4)*8 .. +7.
    // lane l: row r = (wv+h*4)*8 + (l>>3), fetches global chunk (l&7)^(r&7)
    // into linear LDS slot (r, l&7).
    const int sr_off = lane >> 3;            // 0..7 within 8-row group
    const int sj     = lane & 7;             // col16 lane slot
    auto stage = [&](int k, int buf) {
        #pragma unroll
        for (int h = 0; h < 2; ++h) {
            const int rblk = wv + h * 4;     // 0..7
            const int r    = rblk * 8 + sr_off;
            const int nb   = nbs[r * 9 + k];
            const int gcol = sj ^ (r & 7);
            const unsigned short* src = xin + nb * 64 + gcol * 8;
            __builtin_amdgcn_global_load_lds(
                (const __attribute__((address_space(1))) unsigned int*)src,
                (__attribute__((address_space(3))) unsigned int*)&gA[buf][rblk * 8][0],
                16, 0, 0);
        }
    };

    // 3-deep pipeline over 9 taps, 4 rotating buffers
    stage(0, 0); stage(1, 1); stage(2, 2);

    #pragma unroll
    for (int k = 0; k < KT; ++k) {
        // wait until tap k's loads (this wave's 2) are done; keep later taps in flight
        if (k <= 6)      asm volatile("s_waitcnt vmcnt(4)" ::: "memory");
        else if (k == 7) asm volatile("s_waitcnt vmcnt(2)" ::: "memory");
        else             asm volatile("s_waitcnt vmcnt(0)" ::: "memory");
        __syncthreads();                      // all waves' tap-k loads landed;
                                              // buf (k-1)&3 fully consumed
        if (k + 3 < KT) stage(k + 3, (k + 3) & 3);

        #pragma unroll
        for (int im = 0; im < 4; ++im) {
            #pragma unroll
            for (int kk = 0; kk < 2; ++kk) {
                const int row  = im * 16 + (lane & 15);
                const int c16  = kk * 4 + (lane >> 4);
                const int swc  = c16 ^ (row & 7);
                bf16x8 a = *(const bf16x8*)&gA[k & 3][row][swc * 8];
                acc[im] = __builtin_amdgcn_mfma_f32_16x16x32_bf16(a, bw[k][kk], acc[im], 0, 0, 0);
            }
        }
    }

    // epilogue: D lane layout col = lane&15, row = (lane>>4)*4 + j  (within 16x16 tile)
    const int ocol = wv * 16 + (lane & 15);
    const int orow = (lane >> 4) * 4;
    const float bv = bias[ocol];
    #pragma unroll
    for (int im = 0; im < 4; ++im) {
        #pragma unroll
        for (int j = 0; j < 4; ++j) {
            const int r = base + im * 16 + orow + j;
            if (r < NV) {
                float v = acc[im][j] + bv;
                if (LAYER == 1) {
                    bfout[r * 64 + ocol] = f2bf(fmaxf(v, 0.f));
                } else {
                    fout[r * 64 + ocol] = v + resid[r * 64 + ocol];
                }
            }
        }
    }
}

extern "C" void kernel_launch(void* const* d_in, const int* in_sizes, int n_in,
                              void* d_out, int out_size, void* d_ws, size_t ws_size,
                              hipStream_t stream) {
    const float* lv  = (const float*)d_in[0];
    const int*   nbr = (const int*)d_in[1];
    const float* w1  = (const float*)d_in[2];
    const float* b1  = (const float*)d_in[3];
    const float* w2  = (const float*)d_in[4];
    const float* b2  = (const float*)d_in[5];
    float* out = (float*)d_out;

    // workspace layout (needs ~73.4 MiB)
    char* ws = (char*)d_ws;
    unsigned short* xbf0 = (unsigned short*)ws;                // 38,400,000 B: bf16 relu(lv)
    unsigned short* xbf1 = (unsigned short*)(ws + 38400000);   // 38,400,000 B: bf16 relu(y1)
    unsigned short* wt1  = (unsigned short*)(ws + 76800000);   // 73,728 B
    unsigned short* wt2  = (unsigned short*)(ws + 76873728);   // 73,728 B

    const int n4blk = (NV * NF / 4 + 255) / 256;               // 18750
    prep_w_kernel<<<18, 256, 0, stream>>>(w1, w2, wt1, wt2);
    prep_x_kernel<<<n4blk, 256, 0, stream>>>(lv, xbf0);
    conv_kernel<1><<<NBLK, 256, 0, stream>>>(xbf0, nbr, wt1, b1, nullptr, xbf1, nullptr);
    conv_kernel<2><<<NBLK, 256, 0, stream>>>(xbf1, nbr, wt2, b2, lv, nullptr, out);
}